// Round 9
// baseline (104.144 us; speedup 1.0000x reference)
//
#include <hip/hip_runtime.h>
#include <hip/hip_bf16.h>

// ---------------------------------------------------------------------------
// Fused SiamCAR head, Round 11: concurrent towers (waves 0-3 cls, 4-7 box),
// spill-fixed. Grid 512, 512 threads, 64KB LDS, 2 blocks/CU, 1 round.
// vs R10: (a) mt-sequential pointwise with fused BN (live accw 32->16,
// af 16->8 regs); (b) next-chunk weight staging issued BEFORE the pred 3x3
// phase (HBM latency hides under pred MFMA). Peak regs ~100 < 128 cap.
// Sequence: corr MFMA -> corr A bf16 @0-32K -> MLP (scratch @49152) ->
//   dT_cls @32-64K -> bfr_cls(regs) -> dT_box -> bfr_box ->
//   shared 8-trip chunk loop (identical barrier counts in both halves).
// ---------------------------------------------------------------------------

typedef __attribute__((ext_vector_type(8))) short  bf16x8;
typedef __attribute__((ext_vector_type(4))) float  f32x4;

union U8 { bf16x8 v; uint4 q; unsigned short u[8]; };

__device__ __forceinline__ float bf2f(unsigned short h){
  union { unsigned int u; float f; } c; c.u = ((unsigned int)h) << 16; return c.f;
}
__device__ __forceinline__ unsigned short f2bf(float f){
  union { float f; unsigned int u; } c; c.f = f;
  unsigned int r = (c.u + 0x7FFFu + ((c.u >> 16) & 1u)) >> 16;  // RNE
  return (unsigned short)r;
}
__device__ __forceinline__ unsigned int f2bf2(float lo, float hi){
  return (unsigned int)f2bf(lo) | ((unsigned int)f2bf(hi) << 16);
}

// corr A tile [64 p][256 pix] bf16, elem index, 16B-chunk XOR swizzle.
__device__ __forceinline__ int swz(int row, int pix){
  return row*256 + (((pix>>3) ^ (row&31))<<3) + (pix&7);
}
// z^T tile [64 p][128 c] bf16, byte offset (256B rows, 16 chunks XOR by p).
__device__ __forceinline__ int zt_off(int p, int c){
  return (p<<8) + ((((c>>3) ^ (p&15)) & 15)<<4) + ((c&7)<<1);
}
// search^T chunk [256 pix][64 c] bf16, byte offset (128B rows, 8 chunks).
__device__ __forceinline__ int sT_off(int pix, int c){
  return (pix<<7) + ((((c>>3) ^ (pix&7) ^ ((pix>>3)&7)) & 7)<<4) + ((c&7)<<1);
}
// d_T [256 pix][64 p] bf16, byte offset.
__device__ __forceinline__ int dT_off(int pix, int p){
  return (pix<<7) + (((((p>>3) ^ pix) & 7)) << 4) + ((p & 7) << 1);
}
// feat_T [256 pix][32 ocl] bf16, byte offset.
__device__ __forceinline__ int fT_off(int pix, int ocl){
  return (pix<<6) + ((((ocl>>3) ^ pix ^ (pix>>2)) & 3) << 4) + ((ocl & 7) << 1);
}
// pw A-tile [32 ocl][64 p] bf16, byte offset.
__device__ __forceinline__ int pA_off(int ocl, int p){
  return (ocl<<7) + (((((p>>3) ^ ocl) & 7)) << 4) + ((p & 7) << 1);
}

// depthwise 3x3 (pad 1), attention folded into weights, streamed; wave owns
// image rows 2w..2w+1; reads corr A (smem+0), writes d_T (dst).
__device__ __forceinline__ void depthwise(
    int lane, int wave, float ap, const float* __restrict__ dw,
    const unsigned short* __restrict__ sA16, unsigned char* __restrict__ dst)
{
  const int p = lane;
  float wd[9];
  #pragma unroll
  for (int k=0;k<9;++k) wd[k] = dw[p*9+k] * ap;
  #pragma unroll
  for (int io=0;io<2;++io){
    const int ir = wave*2 + io;
    float ot[16];
    #pragma unroll
    for (int j=0;j<16;++j) ot[j] = 0.f;
    #pragma unroll
    for (int dr=0;dr<3;++dr){
      const int r = ir-1+dr;
      if (r >= 0 && r < 16){
        unsigned short tr[16];
        *(uint4*)&tr[0] = *(uint4*)&sA16[swz(p, r*16)];
        *(uint4*)&tr[8] = *(uint4*)&sA16[swz(p, r*16 + 8)];
        float rr[16];
        #pragma unroll
        for (int j=0;j<16;++j) rr[j] = bf2f(tr[j]);
        const float w0 = wd[dr*3+0], w1 = wd[dr*3+1], w2 = wd[dr*3+2];
        #pragma unroll
        for (int j=0;j<16;++j){
          float s = w1*rr[j];
          if (j > 0)  s = fmaf(w0, rr[j-1], s);
          if (j < 15) s = fmaf(w2, rr[j+1], s);
          ot[j] += s;
        }
      }
    }
    #pragma unroll
    for (int j=0;j<16;++j)
      *(unsigned short*)(dst + dT_off(ir*16+j, p)) = f2bf(ot[j]);
  }
}

// stage one 32-oc chunk of pw (fp32) -> [32][64] bf16 swizzled; 256 threads
__device__ __forceinline__ void stage_pw256(int t, int oc0,
                                            const float* __restrict__ pw,
                                            unsigned char* __restrict__ dst){
  const int ocl = t >> 3, p0 = (t & 7) << 3;
  const float4 f0 = *(const float4*)&pw[(oc0 + ocl)*64 + p0];
  const float4 f1 = *(const float4*)&pw[(oc0 + ocl)*64 + p0 + 4];
  U8 w;
  w.u[0]=f2bf(f0.x); w.u[1]=f2bf(f0.y); w.u[2]=f2bf(f0.z); w.u[3]=f2bf(f0.w);
  w.u[4]=f2bf(f1.x); w.u[5]=f2bf(f1.y); w.u[6]=f2bf(f1.z); w.u[7]=f2bf(f1.w);
  *(uint4*)(dst + pA_off(ocl, p0)) = w.q;
}

// stage pred weights for one oc-chunk: wA[o][k = tau*32+ocl] bf16; 256 thr
__device__ __forceinline__ void stage_wA256(int t, int oc0, int nout,
                                            const float* __restrict__ pdw,
                                            unsigned char* __restrict__ dst){
  for (int idx = t; idx < nout*288; idx += 256){
    const int o   = idx / 288;
    const int rem = idx - o*288;
    const int tau = rem >> 5, ocl = rem & 31;
    *(unsigned short*)(dst + (idx<<1)) =
        f2bf(pdw[(o*256 + oc0 + ocl)*9 + tau]);
  }
}

__global__ __launch_bounds__(512, 4) void fused_head(
  const float* __restrict__ search, const float* __restrict__ kern,
  const float* __restrict__ ca_w1, const float* __restrict__ ca_b1,
  const float* __restrict__ ca_w2, const float* __restrict__ ca_b2,
  const float* __restrict__ cls_dw, const float* __restrict__ cls_pw,
  const float* __restrict__ cls_bn_g, const float* __restrict__ cls_bn_b,
  const float* __restrict__ cls_bn_m, const float* __restrict__ cls_bn_v,
  const float* __restrict__ cls_pred_w, const float* __restrict__ cls_pred_b,
  const float* __restrict__ box_dw, const float* __restrict__ box_pw,
  const float* __restrict__ box_bn_g, const float* __restrict__ box_bn_b,
  const float* __restrict__ box_bn_m, const float* __restrict__ box_bn_v,
  const float* __restrict__ box_pred_w, const float* __restrict__ box_pred_b,
  const float* __restrict__ adjust, const float* __restrict__ bias_p,
  float* __restrict__ out)
{
  __shared__ __align__(16) unsigned char smem[65536];
  const int b   = blockIdx.x;               // grid 512: one block per batch
  const int tid = threadIdx.x;
  const int lane = tid & 63, wave = tid >> 6;     // 8 waves
  const int l15 = lane & 15, lg = lane >> 4;

  // ---- stage z^T single-bf16 [64 p][128 c] swizzled @0 (16KB)
  unsigned char* zb = smem;
  {
    const float* kb = kern + (size_t)b*7168;       // [112 c][64 p]
    #pragma unroll
    for (int i=0;i<14;++i){
      const int idx = i*512 + tid;
      const int c = idx>>6, p = idx&63;
      *(unsigned short*)(zb + zt_off(p,c)) = f2bf(kb[idx]);
    }
    #pragma unroll
    for (int i=0;i<2;++i){                         // zero-pad c in [112,128)
      const int idx = i*512 + tid;
      const int p = idx>>4, c = 112 + (idx&15);
      *(unsigned short*)(zb + zt_off(p,c)) = 0;
    }
  }

  // ---- corr via MFMA: corr[64 p][256 pix] = z^T(64x112) * search(112x256)
  unsigned char* stb = smem + 16384;       // search^T chunk [256][64] bf16
  const float* sea = search + (size_t)b*28672;
  f32x4 acc[4][2];
  #pragma unroll
  for (int mt=0;mt<4;++mt)
    #pragma unroll
    for (int nt=0;nt<2;++nt) acc[mt][nt] = f32x4{0.f,0.f,0.f,0.f};

  for (int kc=0;kc<2;++kc){
    __syncthreads();                       // stb free (or z staging done)
    #pragma unroll
    for (int i=0;i<8;++i){
      const int f4i = i*512 + tid;
      const int cc = f4i>>6, pix0 = (f4i&63)<<2;
      const int c  = kc*64 + cc;
      float4 v;
      if (c < 112) v = *(const float4*)(sea + c*256 + pix0);
      else         v = make_float4(0.f,0.f,0.f,0.f);
      const float vv[4] = {v.x, v.y, v.z, v.w};
      #pragma unroll
      for (int j=0;j<4;++j)
        *(unsigned short*)(stb + sT_off(pix0+j, cc)) = f2bf(vv[j]);
    }
    __syncthreads();                       // chunk staged
    #pragma unroll
    for (int kt=0;kt<2;++kt){
      U8 bh[2];
      #pragma unroll
      for (int nt=0;nt<2;++nt){
        const int pix = wave*32 + nt*16 + l15;
        bh[nt].q = *(const uint4*)(stb + sT_off(pix, kt*32 + lg*8));
      }
      #pragma unroll
      for (int mt=0;mt<4;++mt){
        U8 ah;
        ah.q = *(const uint4*)(zb + zt_off(mt*16 + l15, kc*64 + kt*32 + lg*8));
        #pragma unroll
        for (int nt=0;nt<2;++nt)
          acc[mt][nt] = __builtin_amdgcn_mfma_f32_16x16x32_bf16(
              ah.v, bh[nt].v, acc[mt][nt], 0, 0, 0);
      }
    }
  }
  __syncthreads();                         // all LDS reads of z/stb drained

  // ---- stage corr UNSCALED bf16 [64][256] swizzled @0 (acc dies after MLP)
  unsigned short* sA16 = (unsigned short*)smem;
  #pragma unroll
  for (int mt=0;mt<4;++mt){
    #pragma unroll
    for (int nt=0;nt<2;++nt){
      const int pix = wave*32 + nt*16 + l15;
      #pragma unroll
      for (int r=0;r<4;++r)
        sA16[swz(mt*16 + lg*4 + r, pix)] = f2bf(acc[mt][nt][r]);
    }
  }

  // ---- row sums -> means + channel-attention MLP (scratch @49152; dead
  //      before d_T overwrites it — barrier after ap hoist)
  float* ws    = (float*)(smem + 49152);          // [8][64] = 2048 B
  float* smean = (float*)(smem + 51200);          // 64 f32
  float* h1    = (float*)(smem + 51456);          // 64 f32
  float* attvG = (float*)(smem + 51712);          // 64 f32
  #pragma unroll
  for (int mt=0;mt<4;++mt){
    #pragma unroll
    for (int r=0;r<4;++r){
      float s = acc[mt][0][r] + acc[mt][1][r];
      s += __shfl_xor(s, 1, 64);
      s += __shfl_xor(s, 2, 64);
      s += __shfl_xor(s, 4, 64);
      s += __shfl_xor(s, 8, 64);
      if (l15 == 0) ws[wave*64 + mt*16 + lg*4 + r] = s;
    }
  }
  __syncthreads();
  if (tid < 64){
    float m = 0.f;
    #pragma unroll
    for (int w=0;w<8;++w) m += ws[w*64 + tid];
    smean[tid] = m * (1.f/256.f);
  }
  __syncthreads();
  if (tid < 64){
    float s = ca_b1[tid];
    const float* wr = ca_w1 + tid*64;
    #pragma unroll 8
    for (int k=0;k<64;++k) s += smean[k]*wr[k];
    h1[tid] = fmaxf(s, 0.f);
  }
  __syncthreads();
  if (tid < 64){
    float s = ca_b2[tid];
    const float* wr = ca_w2 + tid*64;
    #pragma unroll 8
    for (int k=0;k<64;++k) s += h1[k]*wr[k];
    attvG[tid] = 1.f/(1.f + expf(-s));
  }
  __syncthreads();               // attv ready
  const float ap = attvG[lane];
  __syncthreads();               // all attv reads done before d_T overwrite

  const float adj = adjust[0];

  // ---- tower split by wave: waves 0-3 = cls, waves 4-7 = box
  const int half = tid >> 8;                // 0 = cls, 1 = box
  const int ttid = tid & 255;               // tid within tower half
  const int wt   = wave & 3;                // wave index within tower
  const int nout = half ? 4 : 1;

  const float* pwp  = half ? box_pw     : cls_pw;
  const float* bngp = half ? box_bn_g   : cls_bn_g;
  const float* bnbp = half ? box_bn_b   : cls_bn_b;
  const float* bnmp = half ? box_bn_m   : cls_bn_m;
  const float* bnvp = half ? box_bn_v   : cls_bn_v;
  const float* pdwp = half ? box_pred_w : cls_pred_w;
  const float* pdbp = half ? box_pred_b : cls_pred_b;
  float* outp = half ? (out + (size_t)b*1024)
                     : (out + 524288 + (size_t)b*256);

  unsigned char* dT = smem + 32768;

  // ---- depthwise cls -> d_T; cls half caches B-frags; then box likewise
  depthwise(lane, wave, ap, cls_dw, sA16, dT);
  __syncthreads();                          // d_T(cls) complete
  U8 bfr[4][2];
  if (half == 0){
    #pragma unroll
    for (int nt=0;nt<4;++nt)
      #pragma unroll
      for (int ks=0;ks<2;++ks)
        bfr[nt][ks].q = *(const uint4*)(dT +
            dT_off(wt*64 + nt*16 + l15, ks*32 + lg*8));
  }
  __syncthreads();                          // cls frags read; d_T reusable
  depthwise(lane, wave, ap, box_dw, sA16, dT);
  __syncthreads();                          // d_T(box) complete
  if (half == 1){
    #pragma unroll
    for (int nt=0;nt<4;++nt)
      #pragma unroll
      for (int ks=0;ks<2;++ks)
        bfr[nt][ks].q = *(const uint4*)(dT +
            dT_off(wt*64 + nt*16 + l15, ks*32 + lg*8));
  }
  __syncthreads();   // corr A + d_T dead; all of LDS free for the chunk loop

  // ---- per-tower LDS regions for the shared chunk loop
  unsigned char* featb = smem + half*16384;                  // feat_T 16K each
  unsigned char* pwb0  = smem + 32768 + half*8192;           // pw dbuf 2x4096
  unsigned char* wab0  = smem + (half ? 50304 : 49152);      // wA dbuf
  const int wstride = nout*576;                              // bytes per buf
  float* scl = (float*)(smem + 55296 + half*2048);           // 256 f32
  float* bia = scl + 256;                                    // 256 f32

  {
    const float s = bngp[ttid] * rsqrtf(bnvp[ttid] + 1e-5f);
    scl[ttid] = s;
    bia[ttid] = bnbp[ttid] - bnmp[ttid]*s;
  }
  stage_pw256(ttid, 0, pwp, pwb0);
  stage_wA256(ttid, 0, nout, pdwp, wab0);

  // pred accumulators: wave owns image rows 4wt..4wt+3; lane<16 reg = out ch
  f32x4 accp[4];
  #pragma unroll
  for (int nt=0;nt<4;++nt) accp[nt] = f32x4{0.f,0.f,0.f,0.f};

  for (int ch=0; ch<8; ++ch){
    const int buf = ch & 1, oc0 = ch*32;
    __syncthreads();   // staged buf ready; prev pred finished reading feat_T

    // ---- pointwise via MFMA, mt-SEQUENTIAL with fused BN (live accw = 16)
    unsigned char* pAb = pwb0 + buf*4096;
    #pragma unroll
    for (int mt=0;mt<2;++mt){
      U8 af0, af1;
      af0.q = *(const uint4*)(pAb + pA_off(mt*16 + l15, lg*8));
      af1.q = *(const uint4*)(pAb + pA_off(mt*16 + l15, 32 + lg*8));
      f32x4 accw[4];
      #pragma unroll
      for (int nt=0;nt<4;++nt) accw[nt] = f32x4{0.f,0.f,0.f,0.f};
      #pragma unroll
      for (int nt=0;nt<4;++nt){
        accw[nt] = __builtin_amdgcn_mfma_f32_16x16x32_bf16(
            af0.v, bfr[nt][0].v, accw[nt], 0, 0, 0);
        accw[nt] = __builtin_amdgcn_mfma_f32_16x16x32_bf16(
            af1.v, bfr[nt][1].v, accw[nt], 0, 0, 0);
      }
      // BN + ReLU -> feat_T [pix][32 ocl] bf16
      #pragma unroll
      for (int r=0;r<4;++r){
        const int ocl = mt*16 + lg*4 + r;
        const float sc = scl[oc0+ocl], bi = bia[oc0+ocl];
        #pragma unroll
        for (int nt=0;nt<4;++nt){
          const int pix = wt*64 + nt*16 + l15;
          const float v = fmaxf(fmaf(accw[nt][r], sc, bi), 0.f);
          *(unsigned short*)(featb + fT_off(pix, ocl)) = f2bf(v);
        }
      }
    }
    __syncthreads();   // feat_T chunk ready

    // ---- issue next chunk's weight staging EARLY (global-load latency
    //      hides under the pred MFMA phase; writes buf^1, no reader now)
    if (ch < 7){
      stage_pw256(ttid, oc0 + 32, pwp, pwb0 + (buf^1)*4096);
      stage_wA256(ttid, oc0 + 32, nout, pdwp, wab0 + (buf^1)*wstride);
    }

    // ---- pred 3x3 partial via MFMA
    unsigned char* wAb = wab0 + buf*wstride;
    #pragma unroll
    for (int dr=0;dr<3;++dr){
      #pragma unroll
      for (int dc=0;dc<3;++dc){
        const int tau = dr*3 + dc;
        U8 a;
        const int mr = (nout == 4) ? (l15 & 3) : 0;
        a.q = *(const uint4*)(wAb + ((mr*288 + tau*32 + lg*8) << 1));
        if (l15 >= nout) a.q = make_uint4(0u,0u,0u,0u);
        #pragma unroll
        for (int nt=0;nt<4;++nt){
          const int rp = wt*4 + nt + dr - 1;      // uniform per wave
          if (rp >= 0 && rp <= 15){
            const int cp = l15 + dc - 1;
            const int cc = cp < 0 ? 0 : (cp > 15 ? 15 : cp);
            U8 bf;
            bf.q = *(const uint4*)(featb + fT_off(rp*16 + cc, lg*8));
            if (cp != cc) bf.q = make_uint4(0u,0u,0u,0u);
            accp[nt] = __builtin_amdgcn_mfma_f32_16x16x32_bf16(
                a.v, bf.v, accp[nt], 0, 0, 0);
          }
        }
      }
    }
  }

  // ---- epilogue: lanes 0-15 hold out-chs in regs; wave covers rows 4wt..+3
  if (lane < 16){
    #pragma unroll
    for (int nt=0;nt<4;++nt){
      const int rt = wt*4 + nt;
      if (nout == 1){
        outp[rt*16 + lane] = 0.1f*(accp[nt][0] + pdbp[0]);
      } else {
        #pragma unroll
        for (int o=0;o<4;++o)
          outp[o*256 + rt*16 + lane] =
              expf(fmaf(adj, accp[nt][o] + pdbp[o], bias_p[o]));
      }
    }
  }
}

extern "C" void kernel_launch(void* const* d_in, const int* in_sizes, int n_in,
                              void* d_out, int out_size, void* d_ws, size_t ws_size,
                              hipStream_t stream) {
  (void)in_sizes; (void)n_in; (void)d_ws; (void)ws_size; (void)out_size;
  const float* search     = (const float*)d_in[0];
  const float* kern       = (const float*)d_in[1];
  const float* ca_w1      = (const float*)d_in[2];
  const float* ca_b1      = (const float*)d_in[3];
  const float* ca_w2      = (const float*)d_in[4];
  const float* ca_b2      = (const float*)d_in[5];
  const float* cls_dw     = (const float*)d_in[6];
  const float* cls_pw     = (const float*)d_in[7];
  const float* cls_bn_g   = (const float*)d_in[8];
  const float* cls_bn_b   = (const float*)d_in[9];
  const float* cls_bn_m   = (const float*)d_in[10];
  const float* cls_bn_v   = (const float*)d_in[11];
  const float* cls_pred_w = (const float*)d_in[12];
  const float* cls_pred_b = (const float*)d_in[13];
  const float* box_dw     = (const float*)d_in[14];
  const float* box_pw     = (const float*)d_in[15];
  const float* box_bn_g   = (const float*)d_in[16];
  const float* box_bn_b   = (const float*)d_in[17];
  const float* box_bn_m   = (const float*)d_in[18];
  const float* box_bn_v   = (const float*)d_in[19];
  const float* box_pred_w = (const float*)d_in[20];
  const float* box_pred_b = (const float*)d_in[21];
  const float* adjust     = (const float*)d_in[22];
  const float* bias_p     = (const float*)d_in[23];

  hipLaunchKernelGGL(fused_head, dim3(512), dim3(512), 0, stream,
    search, kern, ca_w1, ca_b1, ca_w2, ca_b2,
    cls_dw, cls_pw, cls_bn_g, cls_bn_b, cls_bn_m, cls_bn_v,
    cls_pred_w, cls_pred_b,
    box_dw, box_pw, box_bn_g, box_bn_b, box_bn_m, box_bn_v,
    box_pred_w, box_pred_b, adjust, bias_p,
    (float*)d_out);
}

// Round 10
// 94.133 us; speedup vs baseline: 1.1063x; 1.1063x over previous
//
#include <hip/hip_runtime.h>
#include <hip/hip_bf16.h>

// ---------------------------------------------------------------------------
// Fused SiamCAR head, Round 12: R7 trunk (sequential towers, grid 512,
// 512 thr, 64KB, spill-free) + barrier-halved chunk pipeline.
//  - corr kept UNSCALED bf16-packed in pk[16] regs (R2-proven at 512 thr);
//    each tower re-stages corr A @0-32K, freeing it after depthwise for
//    feat_T DOUBLE-buffer (feat[0]@0, feat[1]@16K).
//  - chunk loop: ONE barrier/iter: {stage pw(i+2),wA(i+1) | pw-MFMA(i+1)->
//    feat[(i+1)&1] | pred(i)<-feat[i&1],waslot[i&1]} -> ~38 barriers vs 52.
//  - mt-sequential pointwise with fused BN (low live regs).
// LDS map per tower: corrA 0-32K (staging+dw only) | d_T 32-64K (dw only) |
//   feat dbuf 0-32K | pwslot 49152+s*4096 | waslot 57344+s*2304 | BN @61952.
// ---------------------------------------------------------------------------

typedef __attribute__((ext_vector_type(8))) short  bf16x8;
typedef __attribute__((ext_vector_type(4))) float  f32x4;

union U8 { bf16x8 v; uint4 q; unsigned short u[8]; };

__device__ __forceinline__ float bf2f(unsigned short h){
  union { unsigned int u; float f; } c; c.u = ((unsigned int)h) << 16; return c.f;
}
__device__ __forceinline__ unsigned short f2bf(float f){
  union { float f; unsigned int u; } c; c.f = f;
  unsigned int r = (c.u + 0x7FFFu + ((c.u >> 16) & 1u)) >> 16;  // RNE
  return (unsigned short)r;
}
__device__ __forceinline__ unsigned int f2bf2(float lo, float hi){
  return (unsigned int)f2bf(lo) | ((unsigned int)f2bf(hi) << 16);
}

// corr A tile [64 p][256 pix] bf16, elem index, 16B-chunk XOR swizzle.
__device__ __forceinline__ int swz(int row, int pix){
  return row*256 + (((pix>>3) ^ (row&31))<<3) + (pix&7);
}
// z^T tile [64 p][128 c] bf16, byte offset (256B rows, 16 chunks XOR by p).
__device__ __forceinline__ int zt_off(int p, int c){
  return (p<<8) + ((((c>>3) ^ (p&15)) & 15)<<4) + ((c&7)<<1);
}
// search^T chunk [256 pix][64 c] bf16, byte offset (128B rows, 8 chunks).
__device__ __forceinline__ int sT_off(int pix, int c){
  return (pix<<7) + ((((c>>3) ^ (pix&7) ^ ((pix>>3)&7)) & 7)<<4) + ((c&7)<<1);
}
// d_T [256 pix][64 p] bf16, byte offset.
__device__ __forceinline__ int dT_off(int pix, int p){
  return (pix<<7) + (((((p>>3) ^ pix) & 7)) << 4) + ((p & 7) << 1);
}
// feat_T [256 pix][32 ocl] bf16, byte offset (within a 16K buffer).
__device__ __forceinline__ int fT_off(int pix, int ocl){
  return (pix<<6) + ((((ocl>>3) ^ pix ^ (pix>>2)) & 3) << 4) + ((ocl & 7) << 1);
}
// pw A-tile [32 ocl][64 p] bf16, byte offset.
__device__ __forceinline__ int pA_off(int ocl, int p){
  return (ocl<<7) + (((((p>>3) ^ ocl) & 7)) << 4) + ((p & 7) << 1);
}

// stage one 32-oc chunk of pw (fp32 global) -> [32][64] bf16 swizzled (512 thr)
__device__ __forceinline__ void stage_pw(int tid, int oc0,
                                         const float* __restrict__ pw,
                                         unsigned char* __restrict__ dst){
  const int ocl = tid >> 4, p0 = (tid & 15) << 2;
  const float4 f0 = *(const float4*)&pw[(oc0 + ocl)*64 + p0];
  uint2 w; w.x = f2bf2(f0.x, f0.y); w.y = f2bf2(f0.z, f0.w);
  *(uint2*)(dst + pA_off(ocl, p0)) = w;
}

// stage pred weights for one oc-chunk: wA[o][k = tau*32 + ocl] bf16 (512 thr)
template<int NOUT>
__device__ __forceinline__ void stage_wA(int tid, int oc0,
                                         const float* __restrict__ pdw,
                                         unsigned char* __restrict__ dst){
  #pragma unroll
  for (int i=0;i<(NOUT*288+511)/512;++i){
    const int idx = i*512 + tid;
    if (idx < NOUT*288){
      const int o   = idx / 288;
      const int rem = idx - o*288;
      const int tau = rem >> 5, ocl = rem & 31;
      *(unsigned short*)(dst + (idx<<1)) =
          f2bf(pdw[(o*256 + oc0 + ocl)*9 + tau]);
    }
  }
}

template<int NOUT>
__device__ __forceinline__ void run_tower(
    int tid, float ap, const unsigned int pk[16],
    const float* __restrict__ dw,  const float* __restrict__ pw,
    const float* __restrict__ bng, const float* __restrict__ bnb,
    const float* __restrict__ bnm, const float* __restrict__ bnv,
    const float* __restrict__ pdw, const float* __restrict__ pdb,
    float* __restrict__ outp, float adj, const float* __restrict__ biasp,
    unsigned char* smem)
{
  const int lane = tid & 63, wave = tid >> 6;      // 8 waves
  const int l15 = lane & 15, lg = lane >> 4;
  unsigned short* sA16 = (unsigned short*)smem;    // corr A [64][256]

  // ---- stage corr A (unscaled bf16, swizzled) from pk registers
  #pragma unroll
  for (int mt=0;mt<4;++mt){
    #pragma unroll
    for (int nt=0;nt<2;++nt){
      const int pix = wave*32 + nt*16 + l15;
      #pragma unroll
      for (int rp=0;rp<2;++rp){
        const unsigned int v = pk[(mt*2+nt)*2+rp];
        const int p = mt*16 + lg*4 + rp*2;
        sA16[swz(p,   pix)] = (unsigned short)(v & 0xffffu);
        sA16[swz(p+1, pix)] = (unsigned short)(v >> 16);
      }
    }
  }
  __syncthreads();   // corr A complete

  // ---- depthwise 3x3 (pad 1), attention folded into weights, streamed;
  //      wave owns image rows 2w..2w+1; writes d_T @32768
  {
    const int p = lane;
    unsigned char* dT = smem + 32768;
    float wd[9];
    #pragma unroll
    for (int k=0;k<9;++k) wd[k] = dw[p*9+k] * ap;
    #pragma unroll
    for (int io=0;io<2;++io){
      const int ir = wave*2 + io;
      float ot[16];
      #pragma unroll
      for (int j=0;j<16;++j) ot[j] = 0.f;
      #pragma unroll
      for (int dr=0;dr<3;++dr){
        const int r = ir-1+dr;
        if (r >= 0 && r < 16){
          unsigned short tr[16];
          *(uint4*)&tr[0] = *(uint4*)&sA16[swz(p, r*16)];
          *(uint4*)&tr[8] = *(uint4*)&sA16[swz(p, r*16 + 8)];
          float rr[16];
          #pragma unroll
          for (int j=0;j<16;++j) rr[j] = bf2f(tr[j]);
          const float w0 = wd[dr*3+0], w1 = wd[dr*3+1], w2 = wd[dr*3+2];
          #pragma unroll
          for (int j=0;j<16;++j){
            float s = w1*rr[j];
            if (j > 0)  s = fmaf(w0, rr[j-1], s);
            if (j < 15) s = fmaf(w2, rr[j+1], s);
            ot[j] += s;
          }
        }
      }
      #pragma unroll
      for (int j=0;j<16;++j)
        *(unsigned short*)(dT + dT_off(ir*16+j, p)) = f2bf(ot[j]);
    }
  }
  __syncthreads();   // d_T complete (cross-lane handoff)

  // ---- pointwise B-operand chunk-invariant: cache wave's 32 pix in 16 VGPRs
  U8 bfr[2][2];
  #pragma unroll
  for (int nt=0;nt<2;++nt)
    #pragma unroll
    for (int ks=0;ks<2;++ks)
      bfr[nt][ks].q = *(const uint4*)(smem + 32768 +
          dT_off(wave*32 + nt*16 + l15, ks*32 + lg*8));
  __syncthreads();   // corr A + d_T dead; all LDS free

  // ---- BN tables + initial staging: pw(0)->slot0, pw(1)->slot1, wA(0)->w0
  float* scl = (float*)(smem + 61952);       // 256 f32
  float* bia = (float*)(smem + 62976);       // 256 f32
  if (tid < 256){
    const float s = bng[tid] * rsqrtf(bnv[tid] + 1e-5f);
    scl[tid] = s;
    bia[tid] = bnb[tid] - bnm[tid]*s;
  }
  stage_pw(tid, 0,  pw, smem + 49152);
  stage_pw(tid, 32, pw, smem + 53248);
  stage_wA<NOUT>(tid, 0, pdw, smem + 57344);
  __syncthreads();

  // helper lambda: pointwise chunk c -> feat[c&1] (mt-sequential, fused BN)
  auto pw_chunk = [&](int c){
    unsigned char* pAb   = smem + 49152 + (c&1)*4096;
    unsigned char* featb = smem + (c&1)*16384;
    const int oc0 = c*32;
    #pragma unroll
    for (int mt=0;mt<2;++mt){
      U8 af0, af1;
      af0.q = *(const uint4*)(pAb + pA_off(mt*16 + l15, lg*8));
      af1.q = *(const uint4*)(pAb + pA_off(mt*16 + l15, 32 + lg*8));
      f32x4 accw[2];
      accw[0] = f32x4{0.f,0.f,0.f,0.f};
      accw[1] = f32x4{0.f,0.f,0.f,0.f};
      #pragma unroll
      for (int nt=0;nt<2;++nt){
        accw[nt] = __builtin_amdgcn_mfma_f32_16x16x32_bf16(
            af0.v, bfr[nt][0].v, accw[nt], 0, 0, 0);
        accw[nt] = __builtin_amdgcn_mfma_f32_16x16x32_bf16(
            af1.v, bfr[nt][1].v, accw[nt], 0, 0, 0);
      }
      #pragma unroll
      for (int r=0;r<4;++r){
        const int ocl = mt*16 + lg*4 + r;
        const float sc = scl[oc0+ocl], bi = bia[oc0+ocl];
        #pragma unroll
        for (int nt=0;nt<2;++nt){
          const int pix = wave*32 + nt*16 + l15;
          const float v = fmaxf(fmaf(accw[nt][r], sc, bi), 0.f);
          *(unsigned short*)(featb + fT_off(pix, ocl)) = f2bf(v);
        }
      }
    }
  };

  // ---- prologue: compute feat chunk 0
  pw_chunk(0);
  __syncthreads();

  // pred accumulators: wave owns image rows 2w..2w+1; lane<16 reg = out ch
  f32x4 accp[2];
  accp[0] = f32x4{0.f,0.f,0.f,0.f};
  accp[1] = f32x4{0.f,0.f,0.f,0.f};

  // ---- pipelined chunk loop: ONE barrier per iteration
  for (int i=0; i<8; ++i){
    // stage pw(i+2) -> pwslot[i&1] (read by pw_chunk(i) last iter, done)
    if (i < 6) stage_pw(tid, (i+2)*32, pw, smem + 49152 + (i&1)*4096);
    // stage wA(i+1) -> waslot[(i+1)&1] (read by pred(i-1) last iter, done)
    if (i < 7) stage_wA<NOUT>(tid, (i+1)*32, pdw,
                              smem + 57344 + ((i+1)&1)*2304);
    // pointwise chunk i+1 -> feat[(i+1)&1] (pred below reads feat[i&1])
    if (i < 7) pw_chunk(i+1);

    // ---- pred 3x3 partial for chunk i
    unsigned char* featb = smem + (i&1)*16384;
    unsigned char* wAb   = smem + 57344 + (i&1)*2304;
    #pragma unroll
    for (int dr=0;dr<3;++dr){
      #pragma unroll
      for (int dc=0;dc<3;++dc){
        const int tau = dr*3 + dc;
        U8 a;
        const int mr = (NOUT == 4) ? (l15 & 3) : 0;
        a.q = *(const uint4*)(wAb + ((mr*288 + tau*32 + lg*8) << 1));
        if (l15 >= NOUT) a.q = make_uint4(0u,0u,0u,0u);
        #pragma unroll
        for (int nt=0;nt<2;++nt){
          const int rp = wave*2 + nt + dr - 1;      // uniform per wave
          if (rp >= 0 && rp <= 15){
            const int cp = l15 + dc - 1;
            const int cc = cp < 0 ? 0 : (cp > 15 ? 15 : cp);
            U8 bf;
            bf.q = *(const uint4*)(featb + fT_off(rp*16 + cc, lg*8));
            if (cp != cc) bf.q = make_uint4(0u,0u,0u,0u);
            accp[nt] = __builtin_amdgcn_mfma_f32_16x16x32_bf16(
                a.v, bf.v, accp[nt], 0, 0, 0);
          }
        }
      }
    }
    __syncthreads();
  }

  // ---- epilogue: lanes 0-15 hold out-chs in regs; wave covers rows 2w..2w+1
  if (lane < 16){
    #pragma unroll
    for (int nt=0;nt<2;++nt){
      const int rt = wave*2 + nt;
      if constexpr (NOUT == 1){
        outp[rt*16 + lane] = 0.1f*(accp[nt][0] + pdb[0]);
      } else {
        #pragma unroll
        for (int o=0;o<4;++o)
          outp[o*256 + rt*16 + lane] =
              expf(fmaf(adj, accp[nt][o] + pdb[o], biasp[o]));
      }
    }
  }
  // loop's final barrier already synced feat reads; epilogue touches no LDS,
  // so the next tower's corr-A staging (@0-32K) is safe.
}

__global__ __launch_bounds__(512, 4) void fused_head(
  const float* __restrict__ search, const float* __restrict__ kern,
  const float* __restrict__ ca_w1, const float* __restrict__ ca_b1,
  const float* __restrict__ ca_w2, const float* __restrict__ ca_b2,
  const float* __restrict__ cls_dw, const float* __restrict__ cls_pw,
  const float* __restrict__ cls_bn_g, const float* __restrict__ cls_bn_b,
  const float* __restrict__ cls_bn_m, const float* __restrict__ cls_bn_v,
  const float* __restrict__ cls_pred_w, const float* __restrict__ cls_pred_b,
  const float* __restrict__ box_dw, const float* __restrict__ box_pw,
  const float* __restrict__ box_bn_g, const float* __restrict__ box_bn_b,
  const float* __restrict__ box_bn_m, const float* __restrict__ box_bn_v,
  const float* __restrict__ box_pred_w, const float* __restrict__ box_pred_b,
  const float* __restrict__ adjust, const float* __restrict__ bias_p,
  float* __restrict__ out)
{
  __shared__ __align__(16) unsigned char smem[65536];
  const int b   = blockIdx.x;               // grid 512: one block per batch
  const int tid = threadIdx.x;
  const int lane = tid & 63, wave = tid >> 6;     // 8 waves
  const int l15 = lane & 15, lg = lane >> 4;

  // ---- stage z^T single-bf16 [64 p][128 c] swizzled @0 (16KB)
  unsigned char* zb = smem;
  {
    const float* kb = kern + (size_t)b*7168;       // [112 c][64 p]
    #pragma unroll
    for (int i=0;i<14;++i){
      const int idx = i*512 + tid;
      const int c = idx>>6, p = idx&63;
      *(unsigned short*)(zb + zt_off(p,c)) = f2bf(kb[idx]);
    }
    #pragma unroll
    for (int i=0;i<2;++i){                         // zero-pad c in [112,128)
      const int idx = i*512 + tid;
      const int p = idx>>4, c = 112 + (idx&15);
      *(unsigned short*)(zb + zt_off(p,c)) = 0;
    }
  }

  // ---- corr via MFMA: corr[64 p][256 pix] = z^T(64x112) * search(112x256)
  unsigned char* stb = smem + 16384;       // search^T chunk [256][64] bf16
  const float* sea = search + (size_t)b*28672;
  f32x4 acc[4][2];
  #pragma unroll
  for (int mt=0;mt<4;++mt)
    #pragma unroll
    for (int nt=0;nt<2;++nt) acc[mt][nt] = f32x4{0.f,0.f,0.f,0.f};

  for (int kc=0;kc<2;++kc){
    __syncthreads();                       // stb free (or z staging done)
    #pragma unroll
    for (int i=0;i<8;++i){
      const int f4i = i*512 + tid;
      const int cc = f4i>>6, pix0 = (f4i&63)<<2;
      const int c  = kc*64 + cc;
      float4 v;
      if (c < 112) v = *(const float4*)(sea + c*256 + pix0);
      else         v = make_float4(0.f,0.f,0.f,0.f);
      const float vv[4] = {v.x, v.y, v.z, v.w};
      #pragma unroll
      for (int j=0;j<4;++j)
        *(unsigned short*)(stb + sT_off(pix0+j, cc)) = f2bf(vv[j]);
    }
    __syncthreads();                       // chunk staged
    #pragma unroll
    for (int kt=0;kt<2;++kt){
      U8 bh[2];
      #pragma unroll
      for (int nt=0;nt<2;++nt){
        const int pix = wave*32 + nt*16 + l15;
        bh[nt].q = *(const uint4*)(stb + sT_off(pix, kt*32 + lg*8));
      }
      #pragma unroll
      for (int mt=0;mt<4;++mt){
        U8 ah;
        ah.q = *(const uint4*)(zb + zt_off(mt*16 + l15, kc*64 + kt*32 + lg*8));
        #pragma unroll
        for (int nt=0;nt<2;++nt)
          acc[mt][nt] = __builtin_amdgcn_mfma_f32_16x16x32_bf16(
              ah.v, bh[nt].v, acc[mt][nt], 0, 0, 0);
      }
    }
  }
  __syncthreads();                         // all LDS reads of z/stb drained

  // ---- row sums (from acc) -> means + MLP; pack corr UNSCALED to pk regs
  float* ws    = (float*)(smem + 49152);          // [8][64] = 2048 B
  float* smean = (float*)(smem + 51200);          // 64 f32
  float* h1    = (float*)(smem + 51456);          // 64 f32
  float* attvG = (float*)(smem + 51712);          // 64 f32
  #pragma unroll
  for (int mt=0;mt<4;++mt){
    #pragma unroll
    for (int r=0;r<4;++r){
      float s = acc[mt][0][r] + acc[mt][1][r];
      s += __shfl_xor(s, 1, 64);
      s += __shfl_xor(s, 2, 64);
      s += __shfl_xor(s, 4, 64);
      s += __shfl_xor(s, 8, 64);
      if (l15 == 0) ws[wave*64 + mt*16 + lg*4 + r] = s;
    }
  }
  // pack corr to pk[16] (acc dies after this + row sums above)
  unsigned int pk[16];
  #pragma unroll
  for (int mt=0;mt<4;++mt)
    #pragma unroll
    for (int nt=0;nt<2;++nt)
      #pragma unroll
      for (int rp=0;rp<2;++rp)
        pk[(mt*2+nt)*2+rp] = f2bf2(acc[mt][nt][rp*2], acc[mt][nt][rp*2+1]);
  __syncthreads();
  if (tid < 64){
    float m = 0.f;
    #pragma unroll
    for (int w=0;w<8;++w) m += ws[w*64 + tid];
    smean[tid] = m * (1.f/256.f);
  }
  __syncthreads();
  if (tid < 64){
    float s = ca_b1[tid];
    const float* wr = ca_w1 + tid*64;
    #pragma unroll 8
    for (int k=0;k<64;++k) s += smean[k]*wr[k];
    h1[tid] = fmaxf(s, 0.f);
  }
  __syncthreads();
  if (tid < 64){
    float s = ca_b2[tid];
    const float* wr = ca_w2 + tid*64;
    #pragma unroll 8
    for (int k=0;k<64;++k) s += h1[k]*wr[k];
    attvG[tid] = 1.f/(1.f + expf(-s));
  }
  __syncthreads();               // attv ready
  const float ap = attvG[lane];
  __syncthreads();               // all attv reads done before towers reuse LDS

  const float adj = adjust[0];

  run_tower<1>(tid, ap, pk, cls_dw, cls_pw, cls_bn_g, cls_bn_b, cls_bn_m,
               cls_bn_v, cls_pred_w, cls_pred_b,
               out + 524288 + (size_t)b*256, adj, bias_p, smem);
  __syncthreads();               // tower 1 epilogue done before corrA restage
  run_tower<4>(tid, ap, pk, box_dw, box_pw, box_bn_g, box_bn_b, box_bn_m,
               box_bn_v, box_pred_w, box_pred_b,
               out + (size_t)b*1024, adj, bias_p, smem);
}

extern "C" void kernel_launch(void* const* d_in, const int* in_sizes, int n_in,
                              void* d_out, int out_size, void* d_ws, size_t ws_size,
                              hipStream_t stream) {
  (void)in_sizes; (void)n_in; (void)d_ws; (void)ws_size; (void)out_size;
  const float* search     = (const float*)d_in[0];
  const float* kern       = (const float*)d_in[1];
  const float* ca_w1      = (const float*)d_in[2];
  const float* ca_b1      = (const float*)d_in[3];
  const float* ca_w2      = (const float*)d_in[4];
  const float* ca_b2      = (const float*)d_in[5];
  const float* cls_dw     = (const float*)d_in[6];
  const float* cls_pw     = (const float*)d_in[7];
  const float* cls_bn_g   = (const float*)d_in[8];
  const float* cls_bn_b   = (const float*)d_in[9];
  const float* cls_bn_m   = (const float*)d_in[10];
  const float* cls_bn_v   = (const float*)d_in[11];
  const float* cls_pred_w = (const float*)d_in[12];
  const float* cls_pred_b = (const float*)d_in[13];
  const float* box_dw     = (const float*)d_in[14];
  const float* box_pw     = (const float*)d_in[15];
  const float* box_bn_g   = (const float*)d_in[16];
  const float* box_bn_b   = (const float*)d_in[17];
  const float* box_bn_m   = (const float*)d_in[18];
  const float* box_bn_v   = (const float*)d_in[19];
  const float* box_pred_w = (const float*)d_in[20];
  const float* box_pred_b = (const float*)d_in[21];
  const float* adjust     = (const float*)d_in[22];
  const float* bias_p     = (const float*)d_in[23];

  hipLaunchKernelGGL(fused_head, dim3(512), dim3(512), 0, stream,
    search, kern, ca_w1, ca_b1, ca_w2, ca_b2,
    cls_dw, cls_pw, cls_bn_g, cls_bn_b, cls_bn_m, cls_bn_v,
    cls_pred_w, cls_pred_b,
    box_dw, box_pw, box_bn_g, box_bn_b, box_bn_m, box_bn_v,
    box_pred_w, box_pred_b, adjust, bias_p,
    (float*)d_out);
}

// Round 11
// 76.792 us; speedup vs baseline: 1.3562x; 1.2258x over previous
//
#include <hip/hip_runtime.h>
#include <hip/hip_bf16.h>

// ---------------------------------------------------------------------------
// Fused SiamCAR head, Round 13: R7 trunk (sequential towers, grid 512,
// 512 thr, 64KB, 2 blocks/CU, spill-free) + two zero-register optimizations:
//  (1) native HW bf16 converts (__float2bfloat16, RNE) replacing 5-op
//      software RNE — removes ~1500 VALU inst/thread.
//  (2) box tower (runs LAST; corr A dead in its chunk loop) uses feat_T
//      DOUBLE-buffer @0/16K with a 1-barrier/chunk pipeline (R10 invariants,
//      no pk registers needed). cls tower keeps R7's 2-barrier loop.
// Arch-VGPR discipline: at (512,4) the allocator fixes 64 arch + 64 acc;
// every structure exceeding ~64 arch spilled (R8/R9/R10). This adds none.
// ---------------------------------------------------------------------------

typedef __attribute__((ext_vector_type(8))) short  bf16x8;
typedef __attribute__((ext_vector_type(4))) float  f32x4;

union U8 { bf16x8 v; uint4 q; unsigned short u[8]; };

__device__ __forceinline__ float bf2f(unsigned short h){
  union { unsigned int u; float f; } c; c.u = ((unsigned int)h) << 16; return c.f;
}
__device__ __forceinline__ unsigned short f2bf(float f){
  return __bfloat16_as_ushort(__float2bfloat16(f));   // HW cvt, RNE
}
__device__ __forceinline__ unsigned int f2bf2(float lo, float hi){
  return (unsigned int)f2bf(lo) | ((unsigned int)f2bf(hi) << 16);
}

// corr A tile [64 p][256 pix] bf16, elem index, 16B-chunk XOR swizzle.
__device__ __forceinline__ int swz(int row, int pix){
  return row*256 + (((pix>>3) ^ (row&31))<<3) + (pix&7);
}
// z^T tile [64 p][128 c] bf16, byte offset (256B rows, 16 chunks XOR by p).
__device__ __forceinline__ int zt_off(int p, int c){
  return (p<<8) + ((((c>>3) ^ (p&15)) & 15)<<4) + ((c&7)<<1);
}
// search^T chunk [256 pix][64 c] bf16, byte offset (128B rows, 8 chunks).
__device__ __forceinline__ int sT_off(int pix, int c){
  return (pix<<7) + ((((c>>3) ^ (pix&7) ^ ((pix>>3)&7)) & 7)<<4) + ((c&7)<<1);
}
// d_T [256 pix][64 p] bf16, byte offset.
__device__ __forceinline__ int dT_off(int pix, int p){
  return (pix<<7) + (((((p>>3) ^ pix) & 7)) << 4) + ((p & 7) << 1);
}
// feat_T [256 pix][32 ocl] bf16, byte offset (within a 16K buffer).
__device__ __forceinline__ int fT_off(int pix, int ocl){
  return (pix<<6) + ((((ocl>>3) ^ pix ^ (pix>>2)) & 3) << 4) + ((ocl & 7) << 1);
}
// pw A-tile [32 ocl][64 p] bf16, byte offset.
__device__ __forceinline__ int pA_off(int ocl, int p){
  return (ocl<<7) + (((((p>>3) ^ ocl) & 7)) << 4) + ((p & 7) << 1);
}

// stage one 32-oc chunk of pw (fp32 global) -> [32][64] bf16 swizzled (512 thr)
__device__ __forceinline__ void stage_pw(int tid, int oc0,
                                         const float* __restrict__ pw,
                                         unsigned char* __restrict__ dst){
  const int ocl = tid >> 4, p0 = (tid & 15) << 2;
  const float4 f0 = *(const float4*)&pw[(oc0 + ocl)*64 + p0];
  uint2 w; w.x = f2bf2(f0.x, f0.y); w.y = f2bf2(f0.z, f0.w);
  *(uint2*)(dst + pA_off(ocl, p0)) = w;
}

// stage pred weights for one oc-chunk: wA[o][k = tau*32 + ocl] bf16 (512 thr)
template<int NOUT>
__device__ __forceinline__ void stage_wA(int tid, int oc0,
                                         const float* __restrict__ pdw,
                                         unsigned char* __restrict__ dst){
  #pragma unroll
  for (int i=0;i<(NOUT*288+511)/512;++i){
    const int idx = i*512 + tid;
    if (idx < NOUT*288){
      const int o   = idx / 288;
      const int rem = idx - o*288;
      const int tau = rem >> 5, ocl = rem & 31;
      *(unsigned short*)(dst + (idx<<1)) =
          f2bf(pdw[(o*256 + oc0 + ocl)*9 + tau]);
    }
  }
}

template<int NOUT, bool DBUF>
__device__ __forceinline__ void run_tower(
    int tid, float ap,
    const float* __restrict__ dw,  const float* __restrict__ pw,
    const float* __restrict__ bng, const float* __restrict__ bnb,
    const float* __restrict__ bnm, const float* __restrict__ bnv,
    const float* __restrict__ pdw, const float* __restrict__ pdb,
    float* __restrict__ outp, float adj, const float* __restrict__ biasp,
    unsigned char* smem)
{
  const int lane = tid & 63, wave = tid >> 6;      // 8 waves
  const int l15 = lane & 15, lg = lane >> 4;
  unsigned short* sA16 = (unsigned short*)smem;    // corr A [64][256], RO

  // ---- depthwise 3x3 (pad 1), attention folded into weights, streamed;
  //      wave owns image rows 2w..2w+1; writes d_T @32768
  {
    const int p = lane;
    unsigned char* dT = smem + 32768;
    float wd[9];
    #pragma unroll
    for (int k=0;k<9;++k) wd[k] = dw[p*9+k] * ap;
    #pragma unroll
    for (int io=0;io<2;++io){
      const int ir = wave*2 + io;
      float ot[16];
      #pragma unroll
      for (int j=0;j<16;++j) ot[j] = 0.f;
      #pragma unroll
      for (int dr=0;dr<3;++dr){
        const int r = ir-1+dr;
        if (r >= 0 && r < 16){
          unsigned short tr[16];
          *(uint4*)&tr[0] = *(uint4*)&sA16[swz(p, r*16)];
          *(uint4*)&tr[8] = *(uint4*)&sA16[swz(p, r*16 + 8)];
          float rr[16];
          #pragma unroll
          for (int j=0;j<16;++j) rr[j] = bf2f(tr[j]);
          const float w0 = wd[dr*3+0], w1 = wd[dr*3+1], w2 = wd[dr*3+2];
          #pragma unroll
          for (int j=0;j<16;++j){
            float s = w1*rr[j];
            if (j > 0)  s = fmaf(w0, rr[j-1], s);
            if (j < 15) s = fmaf(w2, rr[j+1], s);
            ot[j] += s;
          }
        }
      }
      #pragma unroll
      for (int j=0;j<16;++j)
        *(unsigned short*)(dT + dT_off(ir*16+j, p)) = f2bf(ot[j]);
    }
  }
  __syncthreads();   // d_T complete (cross-lane handoff)

  // ---- pointwise B-operand chunk-invariant: cache wave's 32 pix in 16 VGPRs
  U8 bfr[2][2];
  #pragma unroll
  for (int nt=0;nt<2;++nt)
    #pragma unroll
    for (int ks=0;ks<2;++ks)
      bfr[nt][ks].q = *(const uint4*)(smem + 32768 +
          dT_off(wave*32 + nt*16 + l15, ks*32 + lg*8));
  __syncthreads();   // d_T dead (and for DBUF: corr A dead too)

  // ---- BN tables
  float* scl = (float*)(smem + 61952);       // 256 f32
  float* bia = (float*)(smem + 62976);       // 256 f32
  if (tid < 256){
    const float s = bng[tid] * rsqrtf(bnv[tid] + 1e-5f);
    scl[tid] = s;
    bia[tid] = bnb[tid] - bnm[tid]*s;
  }

  // pred accumulators: wave owns image rows 2w..2w+1; lane<16 reg = out ch
  f32x4 accp[2];
  accp[0] = f32x4{0.f,0.f,0.f,0.f};
  accp[1] = f32x4{0.f,0.f,0.f,0.f};

  // pointwise chunk c (mt-sequential, fused BN) -> featb
  auto pw_chunk = [&](unsigned char* pAb, unsigned char* featb, int oc0){
    #pragma unroll
    for (int mt=0;mt<2;++mt){
      U8 af0, af1;
      af0.q = *(const uint4*)(pAb + pA_off(mt*16 + l15, lg*8));
      af1.q = *(const uint4*)(pAb + pA_off(mt*16 + l15, 32 + lg*8));
      f32x4 accw[2];
      accw[0] = f32x4{0.f,0.f,0.f,0.f};
      accw[1] = f32x4{0.f,0.f,0.f,0.f};
      #pragma unroll
      for (int nt=0;nt<2;++nt){
        accw[nt] = __builtin_amdgcn_mfma_f32_16x16x32_bf16(
            af0.v, bfr[nt][0].v, accw[nt], 0, 0, 0);
        accw[nt] = __builtin_amdgcn_mfma_f32_16x16x32_bf16(
            af1.v, bfr[nt][1].v, accw[nt], 0, 0, 0);
      }
      #pragma unroll
      for (int r=0;r<4;++r){
        const int ocl = mt*16 + lg*4 + r;
        const float sc = scl[oc0+ocl], bi = bia[oc0+ocl];
        #pragma unroll
        for (int nt=0;nt<2;++nt){
          const int pix = wave*32 + nt*16 + l15;
          const float v = fmaxf(fmaf(accw[nt][r], sc, bi), 0.f);
          *(unsigned short*)(featb + fT_off(pix, ocl)) = f2bf(v);
        }
      }
    }
  };

  // pred 3x3 partial for one chunk from featb/wAb
  auto pred_chunk = [&](unsigned char* featb, unsigned char* wAb){
    #pragma unroll
    for (int dr=0;dr<3;++dr){
      #pragma unroll
      for (int dc=0;dc<3;++dc){
        const int tau = dr*3 + dc;
        U8 a;
        const int mr = (NOUT == 4) ? (l15 & 3) : 0;
        a.q = *(const uint4*)(wAb + ((mr*288 + tau*32 + lg*8) << 1));
        if (l15 >= NOUT) a.q = make_uint4(0u,0u,0u,0u);
        #pragma unroll
        for (int nt=0;nt<2;++nt){
          const int rp = wave*2 + nt + dr - 1;      // uniform per wave
          if (rp >= 0 && rp <= 15){
            const int cp = l15 + dc - 1;
            const int cc = cp < 0 ? 0 : (cp > 15 ? 15 : cp);
            U8 bf;
            bf.q = *(const uint4*)(featb + fT_off(rp*16 + cc, lg*8));
            if (cp != cc) bf.q = make_uint4(0u,0u,0u,0u);
            accp[nt] = __builtin_amdgcn_mfma_f32_16x16x32_bf16(
                a.v, bf.v, accp[nt], 0, 0, 0);
          }
        }
      }
    }
  };

  if constexpr (!DBUF){
    // ---- R7-proven 2-barrier chunk loop; feat single-buffer @32768
    stage_pw(tid, 0, pw, smem + 49152);
    stage_wA<NOUT>(tid, 0, pdw, smem + 57344);
    for (int ch=0; ch<8; ++ch){
      const int buf = ch & 1, oc0 = ch*32;
      __syncthreads();   // staged buf ready; prev pred done reading feat
      pw_chunk(smem + 49152 + buf*4096, smem + 32768, oc0);
      __syncthreads();   // feat chunk ready
      if (ch < 7){
        stage_pw(tid, oc0 + 32, pw, smem + 49152 + (buf^1)*4096);
        stage_wA<NOUT>(tid, oc0 + 32, pdw, smem + 57344 + (buf^1)*2304);
      }
      pred_chunk(smem + 32768, smem + 57344 + buf*2304);
    }
    __syncthreads();     // feat/weight reads done before next tower's d_T
  } else {
    // ---- 1-barrier pipelined loop; feat dbuf @0/16K (corr A is dead)
    stage_pw(tid, 0,  pw, smem + 49152);
    stage_pw(tid, 32, pw, smem + 53248);
    stage_wA<NOUT>(tid, 0, pdw, smem + 57344);
    __syncthreads();                       // staging + BN visible
    pw_chunk(smem + 49152, smem + 0, 0);   // feat[0]
    __syncthreads();                       // feat[0] visible
    for (int i=0; i<8; ++i){
      const int s = i & 1;
      if (i < 6) stage_pw(tid, (i+2)*32, pw, smem + 49152 + s*4096);
      if (i < 7) stage_wA<NOUT>(tid, (i+1)*32, pdw,
                                smem + 57344 + ((i+1)&1)*(NOUT*576));
      if (i < 7) pw_chunk(smem + 49152 + ((i+1)&1)*4096,
                          smem + ((i+1)&1)*16384, (i+1)*32);
      pred_chunk(smem + s*16384, smem + 57344 + s*(NOUT*576));
      __syncthreads();
    }
  }

  // ---- epilogue: lanes 0-15 hold out-chs in regs; wave covers rows 2w..2w+1
  if (lane < 16){
    #pragma unroll
    for (int nt=0;nt<2;++nt){
      const int rt = wave*2 + nt;
      if constexpr (NOUT == 1){
        outp[rt*16 + lane] = 0.1f*(accp[nt][0] + pdb[0]);
      } else {
        #pragma unroll
        for (int o=0;o<4;++o)
          outp[o*256 + rt*16 + lane] =
              expf(fmaf(adj, accp[nt][o] + pdb[o], biasp[o]));
      }
    }
  }
}

__global__ __launch_bounds__(512, 4) void fused_head(
  const float* __restrict__ search, const float* __restrict__ kern,
  const float* __restrict__ ca_w1, const float* __restrict__ ca_b1,
  const float* __restrict__ ca_w2, const float* __restrict__ ca_b2,
  const float* __restrict__ cls_dw, const float* __restrict__ cls_pw,
  const float* __restrict__ cls_bn_g, const float* __restrict__ cls_bn_b,
  const float* __restrict__ cls_bn_m, const float* __restrict__ cls_bn_v,
  const float* __restrict__ cls_pred_w, const float* __restrict__ cls_pred_b,
  const float* __restrict__ box_dw, const float* __restrict__ box_pw,
  const float* __restrict__ box_bn_g, const float* __restrict__ box_bn_b,
  const float* __restrict__ box_bn_m, const float* __restrict__ box_bn_v,
  const float* __restrict__ box_pred_w, const float* __restrict__ box_pred_b,
  const float* __restrict__ adjust, const float* __restrict__ bias_p,
  float* __restrict__ out)
{
  __shared__ __align__(16) unsigned char smem[65536];
  const int b   = blockIdx.x;               // grid 512: one block per batch
  const int tid = threadIdx.x;
  const int lane = tid & 63, wave = tid >> 6;     // 8 waves
  const int l15 = lane & 15, lg = lane >> 4;

  // ---- stage z^T single-bf16 [64 p][128 c] swizzled @0 (16KB)
  unsigned char* zb = smem;
  {
    const float* kb = kern + (size_t)b*7168;       // [112 c][64 p]
    #pragma unroll
    for (int i=0;i<14;++i){
      const int idx = i*512 + tid;
      const int c = idx>>6, p = idx&63;
      *(unsigned short*)(zb + zt_off(p,c)) = f2bf(kb[idx]);
    }
    #pragma unroll
    for (int i=0;i<2;++i){                         // zero-pad c in [112,128)
      const int idx = i*512 + tid;
      const int p = idx>>4, c = 112 + (idx&15);
      *(unsigned short*)(zb + zt_off(p,c)) = 0;
    }
  }

  // ---- corr via MFMA: corr[64 p][256 pix] = z^T(64x112) * search(112x256)
  unsigned char* stb = smem + 16384;       // search^T chunk [256][64] bf16
  const float* sea = search + (size_t)b*28672;
  f32x4 acc[4][2];
  #pragma unroll
  for (int mt=0;mt<4;++mt)
    #pragma unroll
    for (int nt=0;nt<2;++nt) acc[mt][nt] = f32x4{0.f,0.f,0.f,0.f};

  for (int kc=0;kc<2;++kc){
    __syncthreads();                       // stb free (or z staging done)
    #pragma unroll
    for (int i=0;i<8;++i){
      const int f4i = i*512 + tid;
      const int cc = f4i>>6, pix0 = (f4i&63)<<2;
      const int c  = kc*64 + cc;
      float4 v;
      if (c < 112) v = *(const float4*)(sea + c*256 + pix0);
      else         v = make_float4(0.f,0.f,0.f,0.f);
      const float vv[4] = {v.x, v.y, v.z, v.w};
      #pragma unroll
      for (int j=0;j<4;++j)
        *(unsigned short*)(stb + sT_off(pix0+j, cc)) = f2bf(vv[j]);
    }
    __syncthreads();                       // chunk staged
    #pragma unroll
    for (int kt=0;kt<2;++kt){
      U8 bh[2];
      #pragma unroll
      for (int nt=0;nt<2;++nt){
        const int pix = wave*32 + nt*16 + l15;
        bh[nt].q = *(const uint4*)(stb + sT_off(pix, kt*32 + lg*8));
      }
      #pragma unroll
      for (int mt=0;mt<4;++mt){
        U8 ah;
        ah.q = *(const uint4*)(zb + zt_off(mt*16 + l15, kc*64 + kt*32 + lg*8));
        #pragma unroll
        for (int nt=0;nt<2;++nt)
          acc[mt][nt] = __builtin_amdgcn_mfma_f32_16x16x32_bf16(
              ah.v, bh[nt].v, acc[mt][nt], 0, 0, 0);
      }
    }
  }
  __syncthreads();                         // all LDS reads of z/stb drained

  // ---- stage corr UNSCALED bf16 [64][256] swizzled @0 (acc dies after MLP)
  unsigned short* sA16 = (unsigned short*)smem;
  #pragma unroll
  for (int mt=0;mt<4;++mt){
    #pragma unroll
    for (int nt=0;nt<2;++nt){
      const int pix = wave*32 + nt*16 + l15;
      #pragma unroll
      for (int r=0;r<4;++r)
        sA16[swz(mt*16 + lg*4 + r, pix)] = f2bf(acc[mt][nt][r]);
    }
  }

  // ---- row sums -> means + channel-attention MLP (scratch @49152; dead
  //      before towers stage weights there — barrier after ap hoist)
  float* ws    = (float*)(smem + 49152);          // [8][64] = 2048 B
  float* smean = (float*)(smem + 51200);          // 64 f32
  float* h1    = (float*)(smem + 51456);          // 64 f32
  float* attvG = (float*)(smem + 51712);          // 64 f32
  #pragma unroll
  for (int mt=0;mt<4;++mt){
    #pragma unroll
    for (int r=0;r<4;++r){
      float s = acc[mt][0][r] + acc[mt][1][r];
      s += __shfl_xor(s, 1, 64);
      s += __shfl_xor(s, 2, 64);
      s += __shfl_xor(s, 4, 64);
      s += __shfl_xor(s, 8, 64);
      if (l15 == 0) ws[wave*64 + mt*16 + lg*4 + r] = s;
    }
  }
  __syncthreads();
  if (tid < 64){
    float m = 0.f;
    #pragma unroll
    for (int w=0;w<8;++w) m += ws[w*64 + tid];
    smean[tid] = m * (1.f/256.f);
  }
  __syncthreads();
  if (tid < 64){
    float s = ca_b1[tid];
    const float* wr = ca_w1 + tid*64;
    #pragma unroll 8
    for (int k=0;k<64;++k) s += smean[k]*wr[k];
    h1[tid] = fmaxf(s, 0.f);
  }
  __syncthreads();
  if (tid < 64){
    float s = ca_b2[tid];
    const float* wr = ca_w2 + tid*64;
    #pragma unroll 8
    for (int k=0;k<64;++k) s += h1[k]*wr[k];
    attvG[tid] = 1.f/(1.f + expf(-s));
  }
  __syncthreads();               // attv ready
  const float ap = attvG[lane];
  __syncthreads();               // attv reads done before towers reuse @49152

  const float adj = adjust[0];

  run_tower<1,false>(tid, ap, cls_dw, cls_pw, cls_bn_g, cls_bn_b, cls_bn_m,
                     cls_bn_v, cls_pred_w, cls_pred_b,
                     out + 524288 + (size_t)b*256, adj, bias_p, smem);
  run_tower<4,true >(tid, ap, box_dw, box_pw, box_bn_g, box_bn_b, box_bn_m,
                     box_bn_v, box_pred_w, box_pred_b,
                     out + (size_t)b*1024, adj, bias_p, smem);
}

extern "C" void kernel_launch(void* const* d_in, const int* in_sizes, int n_in,
                              void* d_out, int out_size, void* d_ws, size_t ws_size,
                              hipStream_t stream) {
  (void)in_sizes; (void)n_in; (void)d_ws; (void)ws_size; (void)out_size;
  const float* search     = (const float*)d_in[0];
  const float* kern       = (const float*)d_in[1];
  const float* ca_w1      = (const float*)d_in[2];
  const float* ca_b1      = (const float*)d_in[3];
  const float* ca_w2      = (const float*)d_in[4];
  const float* ca_b2      = (const float*)d_in[5];
  const float* cls_dw     = (const float*)d_in[6];
  const float* cls_pw     = (const float*)d_in[7];
  const float* cls_bn_g   = (const float*)d_in[8];
  const float* cls_bn_b   = (const float*)d_in[9];
  const float* cls_bn_m   = (const float*)d_in[10];
  const float* cls_bn_v   = (const float*)d_in[11];
  const float* cls_pred_w = (const float*)d_in[12];
  const float* cls_pred_b = (const float*)d_in[13];
  const float* box_dw     = (const float*)d_in[14];
  const float* box_pw     = (const float*)d_in[15];
  const float* box_bn_g   = (const float*)d_in[16];
  const float* box_bn_b   = (const float*)d_in[17];
  const float* box_bn_m   = (const float*)d_in[18];
  const float* box_bn_v   = (const float*)d_in[19];
  const float* box_pred_w = (const float*)d_in[20];
  const float* box_pred_b = (const float*)d_in[21];
  const float* adjust     = (const float*)d_in[22];
  const float* bias_p     = (const float*)d_in[23];

  hipLaunchKernelGGL(fused_head, dim3(512), dim3(512), 0, stream,
    search, kern, ca_w1, ca_b1, ca_w2, ca_b2,
    cls_dw, cls_pw, cls_bn_g, cls_bn_b, cls_bn_m, cls_bn_v,
    cls_pred_w, cls_pred_b,
    box_dw, box_pw, box_bn_g, box_bn_b, box_bn_m, box_bn_v,
    box_pred_w, box_pred_b, adjust, bias_p,
    (float*)d_out);
}

// Round 12
// 68.530 us; speedup vs baseline: 1.5197x; 1.1206x over previous
//
#include <hip/hip_runtime.h>
#include <hip/hip_bf16.h>

// ---------------------------------------------------------------------------
// Fused SiamCAR head, Round 14: EXACT R7 structure (the proven 71.7us
// spill-free trunk: grid 512, 512 thr, 64KB, sequential towers, 2-barrier
// chunk loop, straight-line code) with ONE change: native HW bf16 converts
// (__float2bfloat16, RNE) replacing the 5-op software RNE (~1600 VALU
// inst/thread removed). R11's DBUF box tower spilled (lambdas + slot
// pointers exceeded the 64-arch split) and is reverted.
// LDS map (R7):
//   corr phase : z 0-16K | stb [256pix][64c] 16K-48K | MLP scratch @49152
//   towers     : corr A 0-32K (RO) | d_T 32-64K -> bfr regs -> feat 32-48K |
//                pw dbuf @49152 | wA dbuf @57344 | BN @61952
// ---------------------------------------------------------------------------

typedef __attribute__((ext_vector_type(8))) short  bf16x8;
typedef __attribute__((ext_vector_type(4))) float  f32x4;

union U8 { bf16x8 v; uint4 q; unsigned short u[8]; };

__device__ __forceinline__ float bf2f(unsigned short h){
  union { unsigned int u; float f; } c; c.u = ((unsigned int)h) << 16; return c.f;
}
__device__ __forceinline__ unsigned short f2bf(float f){
  return __bfloat16_as_ushort(__float2bfloat16(f));   // HW cvt, RNE
}
__device__ __forceinline__ unsigned int f2bf2(float lo, float hi){
  return (unsigned int)f2bf(lo) | ((unsigned int)f2bf(hi) << 16);
}

// corr A tile [64 p][256 pix] bf16, elem index, 16B-chunk XOR swizzle.
__device__ __forceinline__ int swz(int row, int pix){
  return row*256 + (((pix>>3) ^ (row&31))<<3) + (pix&7);
}
// z^T tile [64 p][128 c] bf16, byte offset (256B rows, 16 chunks XOR by p).
__device__ __forceinline__ int zt_off(int p, int c){
  return (p<<8) + ((((c>>3) ^ (p&15)) & 15)<<4) + ((c&7)<<1);
}
// search^T chunk [256 pix][64 c] bf16, byte offset (128B rows, 8 chunks).
__device__ __forceinline__ int sT_off(int pix, int c){
  return (pix<<7) + ((((c>>3) ^ (pix&7) ^ ((pix>>3)&7)) & 7)<<4) + ((c&7)<<1);
}
// d_T [256 pix][64 p] bf16, byte offset.
__device__ __forceinline__ int dT_off(int pix, int p){
  return (pix<<7) + (((((p>>3) ^ pix) & 7)) << 4) + ((p & 7) << 1);
}
// feat_T [256 pix][32 ocl] bf16, byte offset.
__device__ __forceinline__ int fT_off(int pix, int ocl){
  return (pix<<6) + ((((ocl>>3) ^ pix ^ (pix>>2)) & 3) << 4) + ((ocl & 7) << 1);
}
// pw A-tile [32 ocl][64 p] bf16, byte offset.
__device__ __forceinline__ int pA_off(int ocl, int p){
  return (ocl<<7) + (((((p>>3) ^ ocl) & 7)) << 4) + ((p & 7) << 1);
}

// stage one 32-oc chunk of pw (fp32 global) -> [32][64] bf16 swizzled (512 thr)
__device__ __forceinline__ void stage_pw(int tid, int oc0,
                                         const float* __restrict__ pw,
                                         unsigned char* __restrict__ dst){
  const int ocl = tid >> 4, p0 = (tid & 15) << 2;
  const float4 f0 = *(const float4*)&pw[(oc0 + ocl)*64 + p0];
  uint2 w; w.x = f2bf2(f0.x, f0.y); w.y = f2bf2(f0.z, f0.w);
  *(uint2*)(dst + pA_off(ocl, p0)) = w;
}

// stage pred weights for one oc-chunk: wA[o][k = tau*32 + ocl] bf16 (512 thr)
template<int NOUT>
__device__ __forceinline__ void stage_wA(int tid, int oc0,
                                         const float* __restrict__ pdw,
                                         unsigned char* __restrict__ dst){
  #pragma unroll
  for (int i=0;i<(NOUT*288+511)/512;++i){
    const int idx = i*512 + tid;
    if (idx < NOUT*288){
      const int o   = idx / 288;
      const int rem = idx - o*288;
      const int tau = rem >> 5, ocl = rem & 31;
      *(unsigned short*)(dst + (idx<<1)) =
          f2bf(pdw[(o*256 + oc0 + ocl)*9 + tau]);
    }
  }
}

template<int NOUT>
__device__ __forceinline__ void run_tower(
    int tid, float ap,
    const float* __restrict__ dw,  const float* __restrict__ pw,
    const float* __restrict__ bng, const float* __restrict__ bnb,
    const float* __restrict__ bnm, const float* __restrict__ bnv,
    const float* __restrict__ pdw, const float* __restrict__ pdb,
    float* __restrict__ outp, float adj, const float* __restrict__ biasp,
    unsigned char* smem)
{
  const int lane = tid & 63, wave = tid >> 6;      // 8 waves
  const int l15 = lane & 15, lg = lane >> 4;
  unsigned short* sA16 = (unsigned short*)smem;    // corr A [64][256], RO

  // ---- depthwise 3x3 (pad 1), attention folded into weights, streamed;
  //      wave owns image rows 2w..2w+1; writes d_T @32768
  {
    const int p = lane;
    unsigned char* dT = smem + 32768;
    float wd[9];
    #pragma unroll
    for (int k=0;k<9;++k) wd[k] = dw[p*9+k] * ap;
    #pragma unroll
    for (int io=0;io<2;++io){
      const int ir = wave*2 + io;
      float ot[16];
      #pragma unroll
      for (int j=0;j<16;++j) ot[j] = 0.f;
      #pragma unroll
      for (int dr=0;dr<3;++dr){
        const int r = ir-1+dr;
        if (r >= 0 && r < 16){
          unsigned short tr[16];
          *(uint4*)&tr[0] = *(uint4*)&sA16[swz(p, r*16)];
          *(uint4*)&tr[8] = *(uint4*)&sA16[swz(p, r*16 + 8)];
          float rr[16];
          #pragma unroll
          for (int j=0;j<16;++j) rr[j] = bf2f(tr[j]);
          const float w0 = wd[dr*3+0], w1 = wd[dr*3+1], w2 = wd[dr*3+2];
          #pragma unroll
          for (int j=0;j<16;++j){
            float s = w1*rr[j];
            if (j > 0)  s = fmaf(w0, rr[j-1], s);
            if (j < 15) s = fmaf(w2, rr[j+1], s);
            ot[j] += s;
          }
        }
      }
      #pragma unroll
      for (int j=0;j<16;++j)
        *(unsigned short*)(dT + dT_off(ir*16+j, p)) = f2bf(ot[j]);
    }
  }
  __syncthreads();   // d_T complete (cross-lane handoff)

  // ---- pointwise B-operand chunk-invariant: cache wave's 32 pix in 16 VGPRs
  U8 bfr[2][2];
  #pragma unroll
  for (int nt=0;nt<2;++nt)
    #pragma unroll
    for (int ks=0;ks<2;++ks)
      bfr[nt][ks].q = *(const uint4*)(smem + 32768 +
          dT_off(wave*32 + nt*16 + l15, ks*32 + lg*8));
  __syncthreads();   // d_T dead; 32K-64K free for feat_T / staging

  // ---- BN scale/bias tables + chunk-0 weight staging
  float* scl = (float*)(smem + 61952);       // 256 f32
  float* bia = (float*)(smem + 62976);       // 256 f32
  if (tid < 256){
    const float s = bng[tid] * rsqrtf(bnv[tid] + 1e-5f);
    scl[tid] = s;
    bia[tid] = bnb[tid] - bnm[tid]*s;
  }
  stage_pw(tid, 0, pw, smem + 49152);
  stage_wA<NOUT>(tid, 0, pdw, smem + 57344);

  // pred accumulators: wave owns image rows 2w..2w+1; lane<16 reg r = out ch
  f32x4 accp[2];
  #pragma unroll
  for (int nt=0;nt<2;++nt) accp[nt] = f32x4{0.f,0.f,0.f,0.f};

  for (int ch=0; ch<8; ++ch){
    const int buf = ch & 1, oc0 = ch*32;
    __syncthreads();   // staged buf ready; prev pred finished reading feat_T

    // ---- pointwise via MFMA: feat[32 oc][256 pix] = pw(32x64) * d(64x256)
    unsigned char* pAb = smem + 49152 + buf*4096;
    U8 af[2][2];
    #pragma unroll
    for (int mt=0;mt<2;++mt)
      #pragma unroll
      for (int ks=0;ks<2;++ks)
        af[mt][ks].q = *(const uint4*)(pAb + pA_off(mt*16 + l15, ks*32 + lg*8));
    f32x4 accw[2][2];
    #pragma unroll
    for (int mt=0;mt<2;++mt)
      #pragma unroll
      for (int nt=0;nt<2;++nt) accw[mt][nt] = f32x4{0.f,0.f,0.f,0.f};
    #pragma unroll
    for (int nt=0;nt<2;++nt){
      #pragma unroll
      for (int mt=0;mt<2;++mt){
        accw[mt][nt] = __builtin_amdgcn_mfma_f32_16x16x32_bf16(
            af[mt][0].v, bfr[nt][0].v, accw[mt][nt], 0, 0, 0);
        accw[mt][nt] = __builtin_amdgcn_mfma_f32_16x16x32_bf16(
            af[mt][1].v, bfr[nt][1].v, accw[mt][nt], 0, 0, 0);
      }
    }
    // BN + ReLU -> feat_T [pix][32 ocl] bf16 @32768
    #pragma unroll
    for (int mt=0;mt<2;++mt){
      #pragma unroll
      for (int r=0;r<4;++r){
        const int ocl = mt*16 + lg*4 + r;
        const float sc = scl[oc0+ocl], bi = bia[oc0+ocl];
        #pragma unroll
        for (int nt=0;nt<2;++nt){
          const int pix = wave*32 + nt*16 + l15;
          const float v = fmaxf(fmaf(accw[mt][nt][r], sc, bi), 0.f);
          *(unsigned short*)(smem + 32768 + fT_off(pix, ocl)) = f2bf(v);
        }
      }
    }
    __syncthreads();   // feat_T chunk ready

    // ---- pred 3x3 partial via MFMA
    unsigned char* wAb = smem + 57344 + buf*2304;
    #pragma unroll
    for (int dr=0;dr<3;++dr){
      #pragma unroll
      for (int dc=0;dc<3;++dc){
        const int tau = dr*3 + dc;
        U8 a;
        const int mr = (NOUT == 4) ? (l15 & 3) : 0;
        a.q = *(const uint4*)(wAb + ((mr*288 + tau*32 + lg*8) << 1));
        if (l15 >= NOUT) a.q = make_uint4(0u,0u,0u,0u);
        #pragma unroll
        for (int nt=0;nt<2;++nt){
          const int rp = wave*2 + nt + dr - 1;      // uniform per wave
          if (rp >= 0 && rp <= 15){
            const int cp = l15 + dc - 1;
            const int cc = cp < 0 ? 0 : (cp > 15 ? 15 : cp);
            U8 bf;
            bf.q = *(const uint4*)(smem + 32768 + fT_off(rp*16 + cc, lg*8));
            if (cp != cc) bf.q = make_uint4(0u,0u,0u,0u);
            accp[nt] = __builtin_amdgcn_mfma_f32_16x16x32_bf16(
                a.v, bf.v, accp[nt], 0, 0, 0);
          }
        }
      }
    }
    // stage next chunk's weights (writes buf^1; no reader this phase)
    if (ch < 7){
      stage_pw(tid, oc0 + 32, pw, smem + 49152 + (buf^1)*4096);
      stage_wA<NOUT>(tid, oc0 + 32, pdw, smem + 57344 + (buf^1)*2304);
    }
  }

  // ---- epilogue: lanes 0-15 hold out-chs in regs; wave covers rows 2w..2w+1
  if (lane < 16){
    #pragma unroll
    for (int nt=0;nt<2;++nt){
      const int rt = wave*2 + nt;
      if constexpr (NOUT == 1){
        outp[rt*16 + lane] = 0.1f*(accp[nt][0] + pdb[0]);
      } else {
        #pragma unroll
        for (int o=0;o<4;++o)
          outp[o*256 + rt*16 + lane] =
              expf(fmaf(adj, accp[nt][o] + pdb[o], biasp[o]));
      }
    }
  }
  __syncthreads();   // feat_T/weight reads done before next tower's d_T write
}

__global__ __launch_bounds__(512, 4) void fused_head(
  const float* __restrict__ search, const float* __restrict__ kern,
  const float* __restrict__ ca_w1, const float* __restrict__ ca_b1,
  const float* __restrict__ ca_w2, const float* __restrict__ ca_b2,
  const float* __restrict__ cls_dw, const float* __restrict__ cls_pw,
  const float* __restrict__ cls_bn_g, const float* __restrict__ cls_bn_b,
  const float* __restrict__ cls_bn_m, const float* __restrict__ cls_bn_v,
  const float* __restrict__ cls_pred_w, const float* __restrict__ cls_pred_b,
  const float* __restrict__ box_dw, const float* __restrict__ box_pw,
  const float* __restrict__ box_bn_g, const float* __restrict__ box_bn_b,
  const float* __restrict__ box_bn_m, const float* __restrict__ box_bn_v,
  const float* __restrict__ box_pred_w, const float* __restrict__ box_pred_b,
  const float* __restrict__ adjust, const float* __restrict__ bias_p,
  float* __restrict__ out)
{
  __shared__ __align__(16) unsigned char smem[65536];
  const int b   = blockIdx.x;               // grid 512: one block per batch
  const int tid = threadIdx.x;
  const int lane = tid & 63, wave = tid >> 6;     // 8 waves
  const int l15 = lane & 15, lg = lane >> 4;

  // ---- stage z^T single-bf16 [64 p][128 c] swizzled @0 (16KB)
  unsigned char* zb = smem;
  {
    const float* kb = kern + (size_t)b*7168;       // [112 c][64 p]
    #pragma unroll
    for (int i=0;i<14;++i){
      const int idx = i*512 + tid;
      const int c = idx>>6, p = idx&63;
      *(unsigned short*)(zb + zt_off(p,c)) = f2bf(kb[idx]);
    }
    #pragma unroll
    for (int i=0;i<2;++i){                         // zero-pad c in [112,128)
      const int idx = i*512 + tid;
      const int p = idx>>4, c = 112 + (idx&15);
      *(unsigned short*)(zb + zt_off(p,c)) = 0;
    }
  }

  // ---- corr via MFMA: corr[64 p][256 pix] = z^T(64x112) * search(112x256)
  unsigned char* stb = smem + 16384;       // search^T chunk [256][64] bf16
  const float* sea = search + (size_t)b*28672;
  f32x4 acc[4][2];
  #pragma unroll
  for (int mt=0;mt<4;++mt)
    #pragma unroll
    for (int nt=0;nt<2;++nt) acc[mt][nt] = f32x4{0.f,0.f,0.f,0.f};

  for (int kc=0;kc<2;++kc){
    __syncthreads();                       // stb free (or z staging done)
    #pragma unroll
    for (int i=0;i<8;++i){
      const int f4i = i*512 + tid;
      const int cc = f4i>>6, pix0 = (f4i&63)<<2;
      const int c  = kc*64 + cc;
      float4 v;
      if (c < 112) v = *(const float4*)(sea + c*256 + pix0);
      else         v = make_float4(0.f,0.f,0.f,0.f);
      const float vv[4] = {v.x, v.y, v.z, v.w};
      #pragma unroll
      for (int j=0;j<4;++j)
        *(unsigned short*)(stb + sT_off(pix0+j, cc)) = f2bf(vv[j]);
    }
    __syncthreads();                       // chunk staged
    #pragma unroll
    for (int kt=0;kt<2;++kt){
      U8 bh[2];
      #pragma unroll
      for (int nt=0;nt<2;++nt){
        const int pix = wave*32 + nt*16 + l15;
        bh[nt].q = *(const uint4*)(stb + sT_off(pix, kt*32 + lg*8));
      }
      #pragma unroll
      for (int mt=0;mt<4;++mt){
        U8 ah;
        ah.q = *(const uint4*)(zb + zt_off(mt*16 + l15, kc*64 + kt*32 + lg*8));
        #pragma unroll
        for (int nt=0;nt<2;++nt)
          acc[mt][nt] = __builtin_amdgcn_mfma_f32_16x16x32_bf16(
              ah.v, bh[nt].v, acc[mt][nt], 0, 0, 0);
      }
    }
  }
  __syncthreads();                         // all LDS reads of z/stb drained

  // ---- stage corr UNSCALED bf16 [64][256] swizzled @0 (acc dies after MLP)
  unsigned short* sA16 = (unsigned short*)smem;
  #pragma unroll
  for (int mt=0;mt<4;++mt){
    #pragma unroll
    for (int nt=0;nt<2;++nt){
      const int pix = wave*32 + nt*16 + l15;
      #pragma unroll
      for (int r=0;r<4;++r)
        sA16[swz(mt*16 + lg*4 + r, pix)] = f2bf(acc[mt][nt][r]);
    }
  }

  // ---- row sums -> means + channel-attention MLP
  // scratch @49152.. (free during/after corr; dead before towers stage pw)
  float* ws    = (float*)(smem + 49152);          // [8][64] = 2048 B
  float* smean = (float*)(smem + 51200);          // 64 f32
  float* h1    = (float*)(smem + 51456);          // 64 f32
  float* attvG = (float*)(smem + 51712);          // 64 f32
  #pragma unroll
  for (int mt=0;mt<4;++mt){
    #pragma unroll
    for (int r=0;r<4;++r){
      float s = acc[mt][0][r] + acc[mt][1][r];
      s += __shfl_xor(s, 1, 64);
      s += __shfl_xor(s, 2, 64);
      s += __shfl_xor(s, 4, 64);
      s += __shfl_xor(s, 8, 64);
      if (l15 == 0) ws[wave*64 + mt*16 + lg*4 + r] = s;
    }
  }
  __syncthreads();
  if (tid < 64){
    float m = 0.f;
    #pragma unroll
    for (int w=0;w<8;++w) m += ws[w*64 + tid];
    smean[tid] = m * (1.f/256.f);
  }
  __syncthreads();
  if (tid < 64){
    float s = ca_b1[tid];
    const float* wr = ca_w1 + tid*64;
    #pragma unroll 8
    for (int k=0;k<64;++k) s += smean[k]*wr[k];
    h1[tid] = fmaxf(s, 0.f);
  }
  __syncthreads();
  if (tid < 64){
    float s = ca_b2[tid];
    const float* wr = ca_w2 + tid*64;
    #pragma unroll 8
    for (int k=0;k<64;++k) s += h1[k]*wr[k];
    attvG[tid] = 1.f/(1.f + expf(-s));
  }
  __syncthreads();               // attv ready
  const float ap = attvG[lane];
  __syncthreads();               // attv reads done before towers reuse @49152

  const float adj = adjust[0];

  run_tower<1>(tid, ap, cls_dw, cls_pw, cls_bn_g, cls_bn_b, cls_bn_m,
               cls_bn_v, cls_pred_w, cls_pred_b,
               out + 524288 + (size_t)b*256, adj, bias_p, smem);
  run_tower<4>(tid, ap, box_dw, box_pw, box_bn_g, box_bn_b, box_bn_m,
               box_bn_v, box_pred_w, box_pred_b,
               out + (size_t)b*1024, adj, bias_p, smem);
}

extern "C" void kernel_launch(void* const* d_in, const int* in_sizes, int n_in,
                              void* d_out, int out_size, void* d_ws, size_t ws_size,
                              hipStream_t stream) {
  (void)in_sizes; (void)n_in; (void)d_ws; (void)ws_size; (void)out_size;
  const float* search     = (const float*)d_in[0];
  const float* kern       = (const float*)d_in[1];
  const float* ca_w1      = (const float*)d_in[2];
  const float* ca_b1      = (const float*)d_in[3];
  const float* ca_w2      = (const float*)d_in[4];
  const float* ca_b2      = (const float*)d_in[5];
  const float* cls_dw     = (const float*)d_in[6];
  const float* cls_pw     = (const float*)d_in[7];
  const float* cls_bn_g   = (const float*)d_in[8];
  const float* cls_bn_b   = (const float*)d_in[9];
  const float* cls_bn_m   = (const float*)d_in[10];
  const float* cls_bn_v   = (const float*)d_in[11];
  const float* cls_pred_w = (const float*)d_in[12];
  const float* cls_pred_b = (const float*)d_in[13];
  const float* box_dw     = (const float*)d_in[14];
  const float* box_pw     = (const float*)d_in[15];
  const float* box_bn_g   = (const float*)d_in[16];
  const float* box_bn_b   = (const float*)d_in[17];
  const float* box_bn_m   = (const float*)d_in[18];
  const float* box_bn_v   = (const float*)d_in[19];
  const float* box_pred_w = (const float*)d_in[20];
  const float* box_pred_b = (const float*)d_in[21];
  const float* adjust     = (const float*)d_in[22];
  const float* bias_p     = (const float*)d_in[23];

  hipLaunchKernelGGL(fused_head, dim3(512), dim3(512), 0, stream,
    search, kern, ca_w1, ca_b1, ca_w2, ca_b2,
    cls_dw, cls_pw, cls_bn_g, cls_bn_b, cls_bn_m, cls_bn_v,
    cls_pred_w, cls_pred_b,
    box_dw, box_pw, box_bn_g, box_bn_b, box_bn_m, box_bn_v,
    box_pred_w, box_pred_b, adjust, bias_p,
    (float*)d_out);
}